// Round 2
// baseline (892.144 us; speedup 1.0000x reference)
//
#include <hip/hip_runtime.h>

// Grouped conv2d N=16 Cin=256 H=W=128 Cout=512 k=3 groups=16 (Cin/g=16, Cout/g=32, pad=1)
// fp32-accurate via bf16 hi/lo split (3 MFMA terms: wh*xh + wh*xl + wl*xh) on
// v_mfma_f32_32x32x16_bf16.
// V2: persistent g-pinned blocks (grid 768 = 16 g x 48 slots = exactly 3 blocks/CU),
//     double-buffered x LDS, register-staged next-tile prefetch (T14), weights loaded
//     once per block from L2 (no weight LDS), row-reuse cuts x ds_reads 36->24/wave.

#define CIN_PG 16
#define COUT_PG 32
#define HH 128
#define WW 128
#define TH 8
#define TW 32
#define XTH 10          // TH + 2
#define XTW 34          // TW + 2
#define NPX 340         // XTH * XTW
#define PLANE 16384     // HH * WW
#define NTILES 1024     // per group: 16 n * 16 ht * 4 wt
#define NSLOTS 48

typedef __attribute__((ext_vector_type(8))) short bf16x8;
typedef __attribute__((ext_vector_type(16))) float f32x16;
typedef __attribute__((ext_vector_type(4))) unsigned int u32x4;

__device__ __forceinline__ unsigned bfpack(float a, float b) {
    unsigned ua = __builtin_bit_cast(unsigned, a);
    unsigned ub = __builtin_bit_cast(unsigned, b);
    return (ua >> 16) | (ub & 0xffff0000u);   // elem0 low half, elem1 high half
}

// ---- prep: W fp32 [512][16][3][3] -> per (g,tap): 2KB laid out for lane-contiguous
//      A-frag loads: [hi: half0 co0..31 | half1 co0..31][lo: same], 16B per (half,co).
//      Lane (co=lane&31, half=lane>>5) reads hi at base + lane*16B, lo at +1KB.
__global__ __launch_bounds__(256) void prep_weights(
    const float* __restrict__ wgt, unsigned* __restrict__ wks)
{
    int t = blockIdx.x * 256 + threadIdx.x;
    if (t >= 16 * COUT_PG * 9) return;
    int tap = t % 9;
    int co  = (t / 9) % COUT_PG;
    int g   = t / (9 * COUT_PG);
    const float* src = wgt + ((size_t)(g * COUT_PG + co) * CIN_PG * 9) + tap;
    float v[16], lo[16];
#pragma unroll
    for (int ci = 0; ci < 16; ++ci) {
        v[ci] = src[ci * 9];
        unsigned ub = __builtin_bit_cast(unsigned, v[ci]);
        float hf = __builtin_bit_cast(float, ub & 0xffff0000u);
        lo[ci] = v[ci] - hf;   // exact in fp32
    }
    u32x4 c0, c1, c2, c3;
#pragma unroll
    for (int j = 0; j < 4; ++j) {
        c0[j] = bfpack(v[2 * j], v[2 * j + 1]);        // hi ci0-7
        c1[j] = bfpack(v[8 + 2 * j], v[9 + 2 * j]);    // hi ci8-15
        c2[j] = bfpack(lo[2 * j], lo[2 * j + 1]);      // lo ci0-7
        c3[j] = bfpack(lo[8 + 2 * j], lo[9 + 2 * j]);  // lo ci8-15
    }
    unsigned* dst = wks + (size_t)(g * 9 + tap) * 512;
    *(u32x4*)(dst + co * 4)       = c0;   // hi, half0
    *(u32x4*)(dst + 128 + co * 4) = c1;   // hi, half1
    *(u32x4*)(dst + 256 + co * 4) = c2;   // lo, half0
    *(u32x4*)(dst + 384 + co * 4) = c3;   // lo, half1
}

// issue 16 global loads (one pixel, all ci) into regs
__device__ __forceinline__ void stage_load(const float* __restrict__ xg,
                                           int h0, int w0, int p, float v[16])
{
    int hh = p / XTW;
    int ww = p - hh * XTW;
    int gh = h0 + hh - 1;
    int gw = w0 + ww - 1;
    if ((unsigned)gh < HH && (unsigned)gw < WW) {
        const float* xp = xg + (size_t)gh * WW + gw;
#pragma unroll
        for (int ci = 0; ci < 16; ++ci) v[ci] = xp[ci * PLANE];
    } else {
#pragma unroll
        for (int ci = 0; ci < 16; ++ci) v[ci] = 0.0f;
    }
}

// convert one pixel to bf16 hi/lo chunks and write 4x b128 to LDS (rotated slots)
__device__ __forceinline__ void stage_write(unsigned* __restrict__ xbuf,
                                            int p, const float v[16])
{
    float lo[16];
#pragma unroll
    for (int ci = 0; ci < 16; ++ci) {
        unsigned ub = __builtin_bit_cast(unsigned, v[ci]);
        float hf = __builtin_bit_cast(float, ub & 0xffff0000u);
        lo[ci] = v[ci] - hf;
    }
    u32x4 c0 = {bfpack(v[0], v[1]), bfpack(v[2], v[3]), bfpack(v[4], v[5]), bfpack(v[6], v[7])};
    u32x4 c1 = {bfpack(v[8], v[9]), bfpack(v[10], v[11]), bfpack(v[12], v[13]), bfpack(v[14], v[15])};
    u32x4 c2 = {bfpack(lo[0], lo[1]), bfpack(lo[2], lo[3]), bfpack(lo[4], lo[5]), bfpack(lo[6], lo[7])};
    u32x4 c3 = {bfpack(lo[8], lo[9]), bfpack(lo[10], lo[11]), bfpack(lo[12], lo[13]), bfpack(lo[14], lo[15])};
    unsigned rot = (p >> 1) & 3;
    unsigned base = (unsigned)p * 16;
    *(u32x4*)&xbuf[base + (((0 + rot) & 3) << 2)] = c0;
    *(u32x4*)&xbuf[base + (((1 + rot) & 3) << 2)] = c1;
    *(u32x4*)&xbuf[base + (((2 + rot) & 3) << 2)] = c2;
    *(u32x4*)&xbuf[base + (((3 + rot) & 3) << 2)] = c3;
}

__global__ __launch_bounds__(256, 3) void grouped_conv_mfma(
    const float* __restrict__ x, const unsigned* __restrict__ wks,
    const float* __restrict__ bias, float* __restrict__ out)
{
    __shared__ unsigned xs[2][NPX * 16];   // 2 x 21760 B double buffer
    __shared__ float bs[COUT_PG];

    const int bx = blockIdx.x;
    const int g = bx & 15;
    const int slot = bx >> 4;          // 0..47
    const int tid = threadIdx.x;
    const int wave = tid >> 6;
    const int lane = tid & 63;
    const int half = lane >> 5;        // ci half
    const int pxl = lane & 31;         // pixel col within tile / co for A-frag

    if (tid < COUT_PG) bs[tid] = bias[g * COUT_PG + tid];

    // ---- A-fragments (all 9 taps, hi+lo) once per block, straight from L2 ----
    bf16x8 wfh[9], wfl[9];
    {
        const unsigned* wg = wks + (size_t)g * (9 * 512);
#pragma unroll
        for (int tap = 0; tap < 9; ++tap) {
            const unsigned* tb = wg + tap * 512;
            wfh[tap] = __builtin_bit_cast(bf16x8, *(const u32x4*)(tb + lane * 4));
            wfl[tap] = __builtin_bit_cast(bf16x8, *(const u32x4*)(tb + 256 + lane * 4));
        }
    }

    // ---- prologue: stage first tile into xs[0] ----
    {
        const int t = slot;
        const int n = t >> 6;
        const int h0 = ((t >> 2) & 15) * TH;
        const int w0 = (t & 3) * TW;
        const float* xg = x + (size_t)(n * 256 + g * CIN_PG) * PLANE;
        float v[16];
        stage_load(xg, h0, w0, tid, v);
        stage_write(xs[0], tid, v);
        if (tid < NPX - 256) {
            stage_load(xg, h0, w0, tid + 256, v);
            stage_write(xs[0], tid + 256, v);
        }
    }

    int cur = 0;
    for (int t = slot; t < NTILES; t += NSLOTS) {
        __syncthreads();   // xs[cur] fully staged by all waves

        const int n = t >> 6;
        const int h0 = ((t >> 2) & 15) * TH;
        const int w0 = (t & 3) * TW;

        // issue next tile's batch-1 loads (latency hides under MFMA rows 0-1)
        const bool hasnext = (t + NSLOTS) < NTILES;
        const float* nxg = x;
        int nh0 = 0, nw0 = 0;
        float v1[16];
        if (hasnext) {
            const int t2 = t + NSLOTS;
            nh0 = ((t2 >> 2) & 15) * TH;
            nw0 = (t2 & 3) * TW;
            nxg = x + (size_t)((t2 >> 6) * 256 + g * CIN_PG) * PLANE;
            stage_load(nxg, nh0, nw0, tid, v1);
        }

        const unsigned* xb = xs[cur];
        f32x16 a0 = {}, a1 = {};
        const int r0 = wave * 2;

        // row loop with reuse: row r feeds a0(kh=r) and a1(kh=r-1)
#pragma unroll
        for (int r = 0; r < 4; ++r) {
            bf16x8 xh[3], xl[3];
#pragma unroll
            for (int kw = 0; kw < 3; ++kw) {
                int p = (r0 + r) * XTW + pxl + kw;
                unsigned a = (unsigned)p * 16 + (((half + ((p >> 1) & 3)) & 3) << 2);
                xh[kw] = __builtin_bit_cast(bf16x8, *(const u32x4*)&xb[a]);
                xl[kw] = __builtin_bit_cast(bf16x8, *(const u32x4*)&xb[a ^ 8]);
            }
            if (r < 3) {
#pragma unroll
                for (int kw = 0; kw < 3; ++kw) {
                    const int tap = r * 3 + kw;
                    a0 = __builtin_amdgcn_mfma_f32_32x32x16_bf16(wfh[tap], xh[kw], a0, 0, 0, 0);
                    a0 = __builtin_amdgcn_mfma_f32_32x32x16_bf16(wfh[tap], xl[kw], a0, 0, 0, 0);
                    a0 = __builtin_amdgcn_mfma_f32_32x32x16_bf16(wfl[tap], xh[kw], a0, 0, 0, 0);
                }
            }
            if (r > 0) {
#pragma unroll
                for (int kw = 0; kw < 3; ++kw) {
                    const int tap = (r - 1) * 3 + kw;
                    a1 = __builtin_amdgcn_mfma_f32_32x32x16_bf16(wfh[tap], xh[kw], a1, 0, 0, 0);
                    a1 = __builtin_amdgcn_mfma_f32_32x32x16_bf16(wfh[tap], xl[kw], a1, 0, 0, 0);
                    a1 = __builtin_amdgcn_mfma_f32_32x32x16_bf16(wfl[tap], xh[kw], a1, 0, 0, 0);
                }
            }
            if (r == 1 && hasnext) {
                // batch-1 arrived under rows 0-1; write it, then issue batch-2
                stage_write(xs[cur ^ 1], tid, v1);
                if (tid < NPX - 256)
                    stage_load(nxg, nh0, nw0, tid + 256, v1);
            }
        }

        // ---- epilogue: D col = lane&31 = px, row = (r&3)+8*(r>>2)+4*half = co ----
        float* ob = out + (size_t)(n * 512 + g * COUT_PG) * PLANE
                  + (size_t)(h0 + r0) * WW + (w0 + pxl);
#pragma unroll
        for (int rr = 0; rr < 16; ++rr) {
            int cor = (rr & 3) + 8 * (rr >> 2) + 4 * half;
            ob[(size_t)cor * PLANE] = a0[rr] + bs[cor];
        }
        ob += WW;
#pragma unroll
        for (int rr = 0; rr < 16; ++rr) {
            int cor = (rr & 3) + 8 * (rr >> 2) + 4 * half;
            ob[(size_t)cor * PLANE] = a1[rr] + bs[cor];
        }

        // batch-2 write (loads covered by the whole row loop + epilogue)
        if (hasnext && tid < NPX - 256)
            stage_write(xs[cur ^ 1], tid + 256, v1);

        cur ^= 1;
    }
}

extern "C" void kernel_launch(void* const* d_in, const int* in_sizes, int n_in,
                              void* d_out, int out_size, void* d_ws, size_t ws_size,
                              hipStream_t stream) {
    const float* x = (const float*)d_in[0];
    const float* w = (const float*)d_in[1];
    const float* b = (const float*)d_in[2];
    float* out = (float*)d_out;
    unsigned* wks = (unsigned*)d_ws;   // needs 294912 B
    hipLaunchKernelGGL(prep_weights, dim3(18), dim3(256), 0, stream, w, wks);
    // persistent: 16 groups x 48 slots = 768 blocks = 3 per CU (all co-resident)
    hipLaunchKernelGGL(grouped_conv_mfma, dim3(768), dim3(256), 0, stream,
                       x, wks, b, out);
}